// Round 6
// baseline (1286.670 us; speedup 1.0000x reference)
//
#include <hip/hip_runtime.h>

typedef _Float16 f16;
typedef f16 f16x8 __attribute__((ext_vector_type(8)));
typedef float f32x4 __attribute__((ext_vector_type(4)));

#define NB 2
#define NC 1152
#define NHW 4096
#define NCH3 3456
#define NC2 2304

#define LO_SCALE 2048.0f
#define LO_INV (1.0f / 2048.0f)

// persistent scratch (fully overwritten every call)
__device__ __align__(16) f16 g_Wcat_h[(size_t)NCH3 * NC];
__device__ __align__(16) f16 g_Wcat_l[(size_t)NCH3 * NC];
__device__ __align__(16) f16 g_WoutB_h[(size_t)NC * NC2];
__device__ __align__(16) f16 g_WoutB_l[(size_t)NC * NC2];
__device__ __align__(16) f16 g_XT_h[(size_t)NB * NHW * NC];
__device__ __align__(16) f16 g_XT_l[(size_t)NB * NHW * NC];
__device__ __align__(16) float g_qkv[(size_t)NB * NCH3 * NHW];
__device__ __align__(16) float g_ms[(size_t)NB * NCH3 * NHW];
__device__ __align__(16) f16 g_attnT_h[(size_t)NB * NHW * NC2];
__device__ __align__(16) f16 g_attnT_l[(size_t)NB * NHW * NC2];
__device__ float g_part[NB * NHW];

__device__ __forceinline__ void gload16(const void* g, void* l) {
  __builtin_amdgcn_global_load_lds(
      (const __attribute__((address_space(1))) unsigned int*)g,
      (__attribute__((address_space(3))) unsigned int*)l, 16, 0, 0);
}

// scaled split: v ~= h + l/2048, with l kept in f16-normal range
__device__ __forceinline__ void split_f16(float v, f16& h, f16& l) {
  h = (f16)v;
  l = (f16)((v - (float)h) * LO_SCALE);
}

// ---------- weight conversion (scaled split hi/lo) ----------
__global__ __launch_bounds__(256) void convert_weights(
    const float* __restrict__ wq, const float* __restrict__ wk,
    const float* __restrict__ wv, const float* __restrict__ wout) {
  size_t idx = ((size_t)blockIdx.x * 256 + threadIdx.x) * 4;
  const size_t NW = (size_t)NC * NC;
  const size_t NWC = 3 * NW;
  const size_t NWO = (size_t)NC * NC2;
  if (idx < NWC) {
    const float* src = (idx < NW) ? wq + idx
                      : (idx < 2 * NW) ? wk + (idx - NW)
                                       : wv + (idx - 2 * NW);
#pragma unroll
    for (int j = 0; j < 4; ++j)
      split_f16(src[j], g_Wcat_h[idx + j], g_Wcat_l[idx + j]);
  } else {
    size_t k = idx - NWC;
    if (k < NWO) {
      const float* src = wout + k;
#pragma unroll
      for (int j = 0; j < 4; ++j)
        split_f16(src[j], g_WoutB_h[k + j], g_WoutB_l[k + j]);
    }
  }
}

// ---------- x (B,C,HW) fp32 -> XT (B,HW,C) scaled-split f16 ----------
__global__ __launch_bounds__(256) void transpose_x(const float* __restrict__ x) {
  __shared__ float tile[32][33];
  int z = blockIdx.z;
  int p0 = blockIdx.x * 32, c0 = blockIdx.y * 32;
  int tx = threadIdx.x, ty = threadIdx.y;
#pragma unroll
  for (int i = 0; i < 32; i += 8)
    tile[ty + i][tx] = x[((size_t)z * NC + c0 + ty + i) * NHW + p0 + tx];
  __syncthreads();
#pragma unroll
  for (int i = 0; i < 32; i += 8) {
    size_t o = ((size_t)z * NHW + p0 + ty + i) * NC + c0 + tx;
    split_f16(tile[tx][ty + i], g_XT_h[o], g_XT_l[o]);
  }
}

// ---------- scaled-split f16 MFMA GEMM: fp32-fidelity ----------
template <int M, int N, int K>
__device__ __forceinline__ void gemm_body_split(
    const f16* __restrict__ Ah, const f16* __restrict__ Al,
    const f16* __restrict__ Bth, const f16* __restrict__ Btl,
    float* __restrict__ C) {
  __shared__ __align__(16) f16 sAh[128 * 32];
  __shared__ __align__(16) f16 sAl[128 * 32];
  __shared__ __align__(16) f16 sBh[128 * 32];
  __shared__ __align__(16) f16 sBl[128 * 32];
  const int tid = threadIdx.x;
  const int lane = tid & 63;
  const int wid = tid >> 6;
  const int wr = wid >> 1, wc = wid & 1;
  const int bm = blockIdx.x * 128, bn = blockIdx.y * 128;
  const size_t boff = (size_t)blockIdx.z * ((size_t)N * K);
  const f16* Bh = Bth + boff;
  const f16* Bl = Btl + boff;
  float* Cb = C + (size_t)blockIdx.z * ((size_t)M * N);
  const int srow = tid >> 2, skb = (tid & 3) * 8;
  const size_t a0 = (size_t)(bm + srow) * K + skb;
  const size_t a1 = (size_t)(bm + 64 + srow) * K + skb;
  const size_t b0 = (size_t)(bn + srow) * K + skb;
  const size_t b1 = (size_t)(bn + 64 + srow) * K + skb;
  const f16 *gAh0 = Ah + a0, *gAh1 = Ah + a1, *gAl0 = Al + a0, *gAl1 = Al + a1;
  const f16 *gBh0 = Bh + b0, *gBh1 = Bh + b1, *gBl0 = Bl + b0, *gBl1 = Bl + b1;
  char* lAh = (char*)sAh + tid * 16;
  char* lAl = (char*)sAl + tid * 16;
  char* lBh = (char*)sBh + tid * 16;
  char* lBl = (char*)sBl + tid * 16;

  f32x4 acc[4][4] = {};
  f32x4 acc2[4][4] = {};
  const int arow = lane & 15, kof = (lane >> 4) * 8;
#pragma unroll 1
  for (int k0 = 0; k0 < K; k0 += 32) {
    gload16(gAh0, lAh); gload16(gAh1, lAh + 4096);
    gload16(gAl0, lAl); gload16(gAl1, lAl + 4096);
    gload16(gBh0, lBh); gload16(gBh1, lBh + 4096);
    gload16(gBl0, lBl); gload16(gBl1, lBl + 4096);
    gAh0 += 32; gAh1 += 32; gAl0 += 32; gAl1 += 32;
    gBh0 += 32; gBh1 += 32; gBl0 += 32; gBl1 += 32;
    __syncthreads();
    f16x8 ah[4], al[4], bh[4], bl[4];
#pragma unroll
    for (int m = 0; m < 4; ++m) {
      int ro = (wr * 64 + m * 16 + arow) * 32 + kof;
      ah[m] = *(const f16x8*)(sAh + ro);
      al[m] = *(const f16x8*)(sAl + ro);
    }
#pragma unroll
    for (int n = 0; n < 4; ++n) {
      int ro = (wc * 64 + n * 16 + arow) * 32 + kof;
      bh[n] = *(const f16x8*)(sBh + ro);
      bl[n] = *(const f16x8*)(sBl + ro);
    }
#pragma unroll
    for (int m = 0; m < 4; ++m)
#pragma unroll
      for (int n = 0; n < 4; ++n) {
        acc[m][n]  = __builtin_amdgcn_mfma_f32_16x16x32_f16(ah[m], bh[n], acc[m][n], 0, 0, 0);
        acc2[m][n] = __builtin_amdgcn_mfma_f32_16x16x32_f16(ah[m], bl[n], acc2[m][n], 0, 0, 0);
        acc2[m][n] = __builtin_amdgcn_mfma_f32_16x16x32_f16(al[m], bh[n], acc2[m][n], 0, 0, 0);
      }
    __syncthreads();
  }
#pragma unroll
  for (int m = 0; m < 4; ++m)
#pragma unroll
    for (int n = 0; n < 4; ++n) {
      int col = bn + wc * 64 + n * 16 + (lane & 15);
#pragma unroll
      for (int j = 0; j < 4; ++j) {
        int row = bm + wr * 64 + m * 16 + (lane >> 4) * 4 + j;
        Cb[(size_t)row * N + col] = acc[m][n][j] + acc2[m][n][j] * LO_INV;
      }
    }
}

__global__ __launch_bounds__(256) void gemm1_kernel() {
  gemm_body_split<NCH3, NHW, NC>(g_Wcat_h, g_Wcat_l, g_XT_h, g_XT_l, g_qkv);
}
__global__ __launch_bounds__(256) void gemm2_kernel(float* __restrict__ out) {
  gemm_body_split<NC, NHW, NC2>(g_WoutB_h, g_WoutB_l, g_attnT_h, g_attnT_l, out);
}

// ---------- fused depthwise 5x5 + grouped 1x1 (fp32) ----------
__global__ __launch_bounds__(256) void conv_kernel(const float* __restrict__ wdw,
                                                   const float* __restrict__ wpw) {
  int z = blockIdx.z, g = blockIdx.y;
  int p = blockIdx.x * 256 + threadIdx.x;
  int h = p >> 6, wx = p & 63;
  const float* base = g_qkv + ((size_t)z * NCH3 + g * 8) * NHW;
  float dw[8];
#pragma unroll
  for (int ci = 0; ci < 8; ++ci) {
    int c = g * 8 + ci;
    const float* wd = wdw + c * 25;
    const float* srcc = base + (size_t)ci * NHW;
    float acc = 0.f;
#pragma unroll
    for (int dy = -2; dy <= 2; ++dy) {
      int hh = h + dy;
      if (hh < 0 || hh > 63) continue;
#pragma unroll
      for (int dx = -2; dx <= 2; ++dx) {
        int ww = wx + dx;
        if (ww < 0 || ww > 63) continue;
        acc += srcc[hh * 64 + ww] * wd[(dy + 2) * 5 + (dx + 2)];
      }
    }
    dw[ci] = acc;
  }
#pragma unroll
  for (int o = 0; o < 8; ++o) {
    const float* wp = wpw + (size_t)(g * 8 + o) * 8;
    float acc = 0.f;
#pragma unroll
    for (int i = 0; i < 8; ++i) acc += wp[i] * dw[i];
    g_ms[((size_t)z * NCH3 + g * 8 + o) * NHW + p] = acc;
  }
}

// ---------- linear attention per (group, batch), fp32 ----------
__global__ __launch_bounds__(256) void attn_kernel() {
  int g = blockIdx.x;
  int z = blockIdx.y;
  int tid = threadIdx.x;
  const float* src = (g < 144)
      ? g_qkv + ((size_t)z * NCH3 + g * 24) * NHW
      : g_ms + ((size_t)z * NCH3 + (g - 144) * 24) * NHW;

  float s[9][8];
#pragma unroll
  for (int d = 0; d < 9; ++d)
#pragma unroll
    for (int e = 0; e < 8; ++e) s[d][e] = 0.f;

  for (int p = tid; p < NHW; p += 256) {
    float kv[8], vv[8];
#pragma unroll
    for (int e = 0; e < 8; ++e) kv[e] = fmaxf(src[(size_t)(8 + e) * NHW + p], 0.f);
#pragma unroll
    for (int d = 0; d < 8; ++d) vv[d] = src[(size_t)(16 + d) * NHW + p];
#pragma unroll
    for (int e = 0; e < 8; ++e) {
#pragma unroll
      for (int d = 0; d < 8; ++d) s[d][e] += vv[d] * kv[e];
      s[8][e] += kv[e];
    }
  }
#pragma unroll
  for (int d = 0; d < 9; ++d)
#pragma unroll
    for (int e = 0; e < 8; ++e) {
      float v = s[d][e];
#pragma unroll
      for (int off = 32; off > 0; off >>= 1) v += __shfl_xor(v, off, 64);
      s[d][e] = v;
    }
  __shared__ float sred[4][72];
  __shared__ float sc[72];
  int w = tid >> 6, lane = tid & 63;
  if (lane == 0) {
#pragma unroll
    for (int d = 0; d < 9; ++d)
#pragma unroll
      for (int e = 0; e < 8; ++e) sred[w][d * 8 + e] = s[d][e];
  }
  __syncthreads();
  if (tid < 72) sc[tid] = sred[0][tid] + sred[1][tid] + sred[2][tid] + sred[3][tid];
  __syncthreads();
  float scl[9][8];
#pragma unroll
  for (int d = 0; d < 9; ++d)
#pragma unroll
    for (int e = 0; e < 8; ++e) scl[d][e] = sc[d * 8 + e];

  for (int p = tid; p < NHW; p += 256) {
    float qv[8];
#pragma unroll
    for (int e = 0; e < 8; ++e) qv[e] = fmaxf(src[(size_t)e * NHW + p], 0.f);
    float o[9];
#pragma unroll
    for (int d = 0; d < 9; ++d) {
      float a = 0.f;
#pragma unroll
      for (int e = 0; e < 8; ++e) a += scl[d][e] * qv[e];
      o[d] = a;
    }
    float r = 1.f / (o[8] + 1e-15f);
    f16x8 oh, ol;
#pragma unroll
    for (int d = 0; d < 8; ++d) {
      float val = o[d] * r;
      f16 h, l;
      split_f16(val, h, l);
      oh[d] = h; ol[d] = l;
    }
    size_t off = ((size_t)z * NHW + p) * NC2 + g * 8;
    *(f16x8*)(g_attnT_h + off) = oh;
    *(f16x8*)(g_attnT_l + off) = ol;
  }
}

// ---------- RMSNorm over channel dim, in-place on y ----------
__global__ __launch_bounds__(256) void rms_zero() {
  g_part[blockIdx.x * 256 + threadIdx.x] = 0.f;
}
__global__ __launch_bounds__(256) void rms_partial(const float* __restrict__ y) {
  int z = blockIdx.z, cc = blockIdx.y;
  int p = blockIdx.x * 256 + threadIdx.x;
  float ss = 0.f;
  int cbase = cc * 144;
  for (int c = 0; c < 144; ++c) {
    float v = y[((size_t)z * NC + cbase + c) * NHW + p];
    ss += v * v;
  }
  atomicAdd(&g_part[z * NHW + p], ss);
}
__global__ __launch_bounds__(256) void rms_norm(float* __restrict__ y,
                                                const float* __restrict__ w,
                                                const float* __restrict__ b) {
  size_t i = ((size_t)blockIdx.x * 256 + threadIdx.x) * 4;
  float4 v = *(const float4*)(y + i);
  int p = (int)(i & (NHW - 1));
  int c = (int)((i >> 12) % NC);
  int z = (int)(i / ((size_t)NC * NHW));
  const float inv = 1.0f / NC;
  float wc = w[c], bc = b[c];
  const float* pp = &g_part[z * NHW + p];
  v.x = v.x * rsqrtf(pp[0] * inv + 1e-5f) * wc + bc;
  v.y = v.y * rsqrtf(pp[1] * inv + 1e-5f) * wc + bc;
  v.z = v.z * rsqrtf(pp[2] * inv + 1e-5f) * wc + bc;
  v.w = v.w * rsqrtf(pp[3] * inv + 1e-5f) * wc + bc;
  *(float4*)(y + i) = v;
}

extern "C" void kernel_launch(void* const* d_in, const int* in_sizes, int n_in,
                              void* d_out, int out_size, void* d_ws, size_t ws_size,
                              hipStream_t stream) {
  const float* x = (const float*)d_in[0];
  const float* wq = (const float*)d_in[1];
  const float* wk = (const float*)d_in[2];
  const float* wv = (const float*)d_in[3];
  const float* wdw = (const float*)d_in[4];
  const float* wpw = (const float*)d_in[5];
  const float* wout = (const float*)d_in[6];
  const float* rw = (const float*)d_in[7];
  const float* rb = (const float*)d_in[8];
  float* y = (float*)d_out;

  convert_weights<<<6480, 256, 0, stream>>>(wq, wk, wv, wout);
  transpose_x<<<dim3(128, 36, 2), dim3(32, 8), 0, stream>>>(x);
  gemm1_kernel<<<dim3(27, 32, 2), 256, 0, stream>>>();
  conv_kernel<<<dim3(16, 432, 2), 256, 0, stream>>>(wdw, wpw);
  attn_kernel<<<dim3(288, 2), 256, 0, stream>>>();
  gemm2_kernel<<<dim3(9, 32, 2), 256, 0, stream>>>(y);
  rms_zero<<<32, 256, 0, stream>>>();
  rms_partial<<<dim3(16, 8, 2), 256, 0, stream>>>(y);
  rms_norm<<<9216, 256, 0, stream>>>(y, rw, rb);
}

// Round 7
// 869.231 us; speedup vs baseline: 1.4802x; 1.4802x over previous
//
#include <hip/hip_runtime.h>

typedef _Float16 f16;
typedef f16 f16x8 __attribute__((ext_vector_type(8)));
typedef float f32x4 __attribute__((ext_vector_type(4)));

#define NB 2
#define NC 1152
#define NHW 4096
#define NCH3 3456
#define NC2 2304

#define LO_SCALE 2048.0f
#define LO_INV (1.0f / 2048.0f)

// persistent scratch (fully overwritten every call)
__device__ __align__(16) f16 g_Wcat_h[(size_t)NCH3 * NC];
__device__ __align__(16) f16 g_Wcat_l[(size_t)NCH3 * NC];
__device__ __align__(16) f16 g_WoutB_h[(size_t)NC * NC2];
__device__ __align__(16) f16 g_XT_h[(size_t)NB * NHW * NC];
__device__ __align__(16) f16 g_XT_l[(size_t)NB * NHW * NC];
__device__ __align__(16) float g_qkv[(size_t)NB * NCH3 * NHW];
__device__ __align__(16) float g_ms[(size_t)NB * NCH3 * NHW];
__device__ __align__(16) f16 g_attnT_h[(size_t)NB * NHW * NC2];
__device__ float g_part[NB * NHW];

__device__ __forceinline__ void gload16(const void* g, void* l) {
  __builtin_amdgcn_global_load_lds(
      (const __attribute__((address_space(1))) unsigned int*)g,
      (__attribute__((address_space(3))) unsigned int*)l, 16, 0, 0);
}

// scaled split: v ~= h + l/2048, with l kept in f16-normal range
__device__ __forceinline__ void split_f16(float v, f16& h, f16& l) {
  h = (f16)v;
  l = (f16)((v - (float)h) * LO_SCALE);
}

// ---------- weight conversion ----------
__global__ __launch_bounds__(256) void convert_weights(
    const float* __restrict__ wq, const float* __restrict__ wk,
    const float* __restrict__ wv, const float* __restrict__ wout) {
  size_t idx = ((size_t)blockIdx.x * 256 + threadIdx.x) * 4;
  const size_t NW = (size_t)NC * NC;
  const size_t NWC = 3 * NW;
  const size_t NWO = (size_t)NC * NC2;
  if (idx < NWC) {
    const float* src = (idx < NW) ? wq + idx
                      : (idx < 2 * NW) ? wk + (idx - NW)
                                       : wv + (idx - 2 * NW);
#pragma unroll
    for (int j = 0; j < 4; ++j)
      split_f16(src[j], g_Wcat_h[idx + j], g_Wcat_l[idx + j]);
  } else {
    size_t k = idx - NWC;
    if (k < NWO) {
      const float* src = wout + k;
#pragma unroll
      for (int j = 0; j < 4; ++j) g_WoutB_h[k + j] = (f16)src[j];
    }
  }
}

// ---------- x (B,C,HW) fp32 -> XT (B,HW,C) scaled-split f16 ----------
__global__ __launch_bounds__(256) void transpose_x(const float* __restrict__ x) {
  __shared__ float tile[32][33];
  int z = blockIdx.z;
  int p0 = blockIdx.x * 32, c0 = blockIdx.y * 32;
  int tx = threadIdx.x, ty = threadIdx.y;
#pragma unroll
  for (int i = 0; i < 32; i += 8)
    tile[ty + i][tx] = x[((size_t)z * NC + c0 + ty + i) * NHW + p0 + tx];
  __syncthreads();
#pragma unroll
  for (int i = 0; i < 32; i += 8) {
    size_t o = ((size_t)z * NHW + p0 + ty + i) * NC + c0 + tx;
    split_f16(tile[tx][ty + i], g_XT_h[o], g_XT_l[o]);
  }
}

// ===== GEMM geometry (both kernels) =====
// 512 threads = 8 waves (2x4). Block tile 128x128, K-step 32.
// LDS tile [128][32] f16, 16B-block swizzle: blk' = blk ^ ((row>>1)&3).
// global_load_lds dest is LINEAR (tid*16); source address pre-swizzled.

// ---------- split-f16 GEMM (fp32 fidelity): C = A @ Bt^T ----------
template <int M, int N, int K>
__device__ __forceinline__ void gemm_body_split(
    const f16* __restrict__ Ah, const f16* __restrict__ Al,
    const f16* __restrict__ Bth, const f16* __restrict__ Btl,
    float* __restrict__ C) {
  __shared__ __align__(16) f16 sAh[128 * 32];
  __shared__ __align__(16) f16 sAl[128 * 32];
  __shared__ __align__(16) f16 sBh[128 * 32];
  __shared__ __align__(16) f16 sBl[128 * 32];
  const int tid = threadIdx.x;
  const int lane = tid & 63;
  const int wid = tid >> 6;
  const int wr = wid >> 2, wc = wid & 3;          // 2x4 waves
  const int bm = blockIdx.x * 128, bn = blockIdx.y * 128;
  const size_t boff = (size_t)blockIdx.z * ((size_t)N * K);
  const f16* Bh = Bth + boff;
  const f16* Bl = Btl + boff;
  float* Cb = C + (size_t)blockIdx.z * ((size_t)M * N);
  // staging: thread -> (row = tid>>2, lds blk = tid&3), source blk swizzled
  const int srow = tid >> 2;
  const int skb = (((tid & 3) ^ ((srow >> 1) & 3)) * 8);
  const f16* gAh = Ah + (size_t)(bm + srow) * K + skb;
  const f16* gAl = Al + (size_t)(bm + srow) * K + skb;
  const f16* gBh = Bh + (size_t)(bn + srow) * K + skb;
  const f16* gBl = Bl + (size_t)(bn + srow) * K + skb;
  char* lAh = (char*)sAh + tid * 16;
  char* lAl = (char*)sAl + tid * 16;
  char* lBh = (char*)sBh + tid * 16;
  char* lBl = (char*)sBl + tid * 16;

  f32x4 acc[4][2] = {};
  f32x4 acc2[4][2] = {};
  const int arow = lane & 15;
  const int swz = (((lane >> 4) ^ ((arow >> 1) & 3)) * 8);  // swizzled 16B blk
#pragma unroll 1
  for (int k0 = 0; k0 < K; k0 += 32) {
    gload16(gAh, lAh);
    gload16(gAl, lAl);
    gload16(gBh, lBh);
    gload16(gBl, lBl);
    gAh += 32; gAl += 32; gBh += 32; gBl += 32;
    __syncthreads();
    f16x8 ah[4], al[4], bh[2], bl[2];
#pragma unroll
    for (int m = 0; m < 4; ++m) {
      int ro = (wr * 64 + m * 16 + arow) * 32 + swz;
      ah[m] = *(const f16x8*)(sAh + ro);
      al[m] = *(const f16x8*)(sAl + ro);
    }
#pragma unroll
    for (int n = 0; n < 2; ++n) {
      int ro = (wc * 32 + n * 16 + arow) * 32 + swz;
      bh[n] = *(const f16x8*)(sBh + ro);
      bl[n] = *(const f16x8*)(sBl + ro);
    }
#pragma unroll
    for (int m = 0; m < 4; ++m)
#pragma unroll
      for (int n = 0; n < 2; ++n) {
        acc[m][n]  = __builtin_amdgcn_mfma_f32_16x16x32_f16(ah[m], bh[n], acc[m][n], 0, 0, 0);
        acc2[m][n] = __builtin_amdgcn_mfma_f32_16x16x32_f16(ah[m], bl[n], acc2[m][n], 0, 0, 0);
        acc2[m][n] = __builtin_amdgcn_mfma_f32_16x16x32_f16(al[m], bh[n], acc2[m][n], 0, 0, 0);
      }
    __syncthreads();
  }
#pragma unroll
  for (int m = 0; m < 4; ++m)
#pragma unroll
    for (int n = 0; n < 2; ++n) {
      int col = bn + wc * 32 + n * 16 + arow;
#pragma unroll
      for (int j = 0; j < 4; ++j) {
        int row = bm + wr * 64 + m * 16 + (lane >> 4) * 4 + j;
        Cb[(size_t)row * N + col] = acc[m][n][j] + acc2[m][n][j] * LO_INV;
      }
    }
}

// ---------- plain f16 GEMM: C = A @ Bt^T ----------
template <int M, int N, int K>
__device__ __forceinline__ void gemm_body_plain(
    const f16* __restrict__ A, const f16* __restrict__ Bt,
    float* __restrict__ C) {
  __shared__ __align__(16) f16 sA[128 * 32];
  __shared__ __align__(16) f16 sB[128 * 32];
  const int tid = threadIdx.x;
  const int lane = tid & 63;
  const int wid = tid >> 6;
  const int wr = wid >> 2, wc = wid & 3;
  const int bm = blockIdx.x * 128, bn = blockIdx.y * 128;
  const f16* Bb = Bt + (size_t)blockIdx.z * ((size_t)N * K);
  float* Cb = C + (size_t)blockIdx.z * ((size_t)M * N);
  const int srow = tid >> 2;
  const int skb = (((tid & 3) ^ ((srow >> 1) & 3)) * 8);
  const f16* gA = A + (size_t)(bm + srow) * K + skb;
  const f16* gB = Bb + (size_t)(bn + srow) * K + skb;
  char* lA = (char*)sA + tid * 16;
  char* lB = (char*)sB + tid * 16;

  f32x4 acc[4][2] = {};
  const int arow = lane & 15;
  const int swz = (((lane >> 4) ^ ((arow >> 1) & 3)) * 8);
#pragma unroll 1
  for (int k0 = 0; k0 < K; k0 += 32) {
    gload16(gA, lA);
    gload16(gB, lB);
    gA += 32; gB += 32;
    __syncthreads();
    f16x8 af[4], bf[2];
#pragma unroll
    for (int m = 0; m < 4; ++m)
      af[m] = *(const f16x8*)(sA + (wr * 64 + m * 16 + arow) * 32 + swz);
#pragma unroll
    for (int n = 0; n < 2; ++n)
      bf[n] = *(const f16x8*)(sB + (wc * 32 + n * 16 + arow) * 32 + swz);
#pragma unroll
    for (int m = 0; m < 4; ++m)
#pragma unroll
      for (int n = 0; n < 2; ++n)
        acc[m][n] = __builtin_amdgcn_mfma_f32_16x16x32_f16(af[m], bf[n], acc[m][n], 0, 0, 0);
    __syncthreads();
  }
#pragma unroll
  for (int m = 0; m < 4; ++m)
#pragma unroll
    for (int n = 0; n < 2; ++n) {
      int col = bn + wc * 32 + n * 16 + arow;
#pragma unroll
      for (int j = 0; j < 4; ++j) {
        int row = bm + wr * 64 + m * 16 + (lane >> 4) * 4 + j;
        Cb[(size_t)row * N + col] = acc[m][n][j];
      }
    }
}

__global__ __launch_bounds__(512) void gemm1_kernel() {
  gemm_body_split<NCH3, NHW, NC>(g_Wcat_h, g_Wcat_l, g_XT_h, g_XT_l, g_qkv);
}
__global__ __launch_bounds__(512) void gemm2_kernel(float* __restrict__ out) {
  gemm_body_plain<NC, NHW, NC2>(g_WoutB_h, g_attnT_h, out);
}

// ---------- fused depthwise 5x5 + grouped 1x1 (fp32) ----------
__global__ __launch_bounds__(256) void conv_kernel(const float* __restrict__ wdw,
                                                   const float* __restrict__ wpw) {
  int z = blockIdx.z, g = blockIdx.y;
  int p = blockIdx.x * 256 + threadIdx.x;
  int h = p >> 6, wx = p & 63;
  const float* base = g_qkv + ((size_t)z * NCH3 + g * 8) * NHW;
  float dw[8];
#pragma unroll
  for (int ci = 0; ci < 8; ++ci) {
    int c = g * 8 + ci;
    const float* wd = wdw + c * 25;
    const float* srcc = base + (size_t)ci * NHW;
    float acc = 0.f;
#pragma unroll
    for (int dy = -2; dy <= 2; ++dy) {
      int hh = h + dy;
      if (hh < 0 || hh > 63) continue;
#pragma unroll
      for (int dx = -2; dx <= 2; ++dx) {
        int ww = wx + dx;
        if (ww < 0 || ww > 63) continue;
        acc += srcc[hh * 64 + ww] * wd[(dy + 2) * 5 + (dx + 2)];
      }
    }
    dw[ci] = acc;
  }
#pragma unroll
  for (int o = 0; o < 8; ++o) {
    const float* wp = wpw + (size_t)(g * 8 + o) * 8;
    float acc = 0.f;
#pragma unroll
    for (int i = 0; i < 8; ++i) acc += wp[i] * dw[i];
    g_ms[((size_t)z * NCH3 + g * 8 + o) * NHW + p] = acc;
  }
}

// ---------- linear attention per (group, batch), fp32 ----------
__global__ __launch_bounds__(256) void attn_kernel() {
  int g = blockIdx.x;
  int z = blockIdx.y;
  int tid = threadIdx.x;
  const float* src = (g < 144)
      ? g_qkv + ((size_t)z * NCH3 + g * 24) * NHW
      : g_ms + ((size_t)z * NCH3 + (g - 144) * 24) * NHW;

  float s[9][8];
#pragma unroll
  for (int d = 0; d < 9; ++d)
#pragma unroll
    for (int e = 0; e < 8; ++e) s[d][e] = 0.f;

  for (int p = tid; p < NHW; p += 256) {
    float kv[8], vv[8];
#pragma unroll
    for (int e = 0; e < 8; ++e) kv[e] = fmaxf(src[(size_t)(8 + e) * NHW + p], 0.f);
#pragma unroll
    for (int d = 0; d < 8; ++d) vv[d] = src[(size_t)(16 + d) * NHW + p];
#pragma unroll
    for (int e = 0; e < 8; ++e) {
#pragma unroll
      for (int d = 0; d < 8; ++d) s[d][e] += vv[d] * kv[e];
      s[8][e] += kv[e];
    }
  }
#pragma unroll
  for (int d = 0; d < 9; ++d)
#pragma unroll
    for (int e = 0; e < 8; ++e) {
      float v = s[d][e];
#pragma unroll
      for (int off = 32; off > 0; off >>= 1) v += __shfl_xor(v, off, 64);
      s[d][e] = v;
    }
  __shared__ float sred[4][72];
  __shared__ float sc[72];
  int w = tid >> 6, lane = tid & 63;
  if (lane == 0) {
#pragma unroll
    for (int d = 0; d < 9; ++d)
#pragma unroll
      for (int e = 0; e < 8; ++e) sred[w][d * 8 + e] = s[d][e];
  }
  __syncthreads();
  if (tid < 72) sc[tid] = sred[0][tid] + sred[1][tid] + sred[2][tid] + sred[3][tid];
  __syncthreads();
  float scl[9][8];
#pragma unroll
  for (int d = 0; d < 9; ++d)
#pragma unroll
    for (int e = 0; e < 8; ++e) scl[d][e] = sc[d * 8 + e];

  for (int p = tid; p < NHW; p += 256) {
    float qv[8];
#pragma unroll
    for (int e = 0; e < 8; ++e) qv[e] = fmaxf(src[(size_t)e * NHW + p], 0.f);
    float o[9];
#pragma unroll
    for (int d = 0; d < 9; ++d) {
      float a = 0.f;
#pragma unroll
      for (int e = 0; e < 8; ++e) a += scl[d][e] * qv[e];
      o[d] = a;
    }
    float r = 1.f / (o[8] + 1e-15f);
    f16x8 oh;
#pragma unroll
    for (int d = 0; d < 8; ++d) oh[d] = (f16)(o[d] * r);
    *(f16x8*)(g_attnT_h + ((size_t)z * NHW + p) * NC2 + g * 8) = oh;
  }
}

// ---------- RMSNorm over channel dim, in-place on y ----------
__global__ __launch_bounds__(256) void rms_zero() {
  g_part[blockIdx.x * 256 + threadIdx.x] = 0.f;
}
__global__ __launch_bounds__(256) void rms_partial(const float* __restrict__ y) {
  int z = blockIdx.z, cc = blockIdx.y;
  int p = blockIdx.x * 256 + threadIdx.x;
  float ss = 0.f;
  int cbase = cc * 144;
  for (int c = 0; c < 144; ++c) {
    float v = y[((size_t)z * NC + cbase + c) * NHW + p];
    ss += v * v;
  }
  atomicAdd(&g_part[z * NHW + p], ss);
}
__global__ __launch_bounds__(256) void rms_norm(float* __restrict__ y,
                                                const float* __restrict__ w,
                                                const float* __restrict__ b) {
  size_t i = ((size_t)blockIdx.x * 256 + threadIdx.x) * 4;
  float4 v = *(const float4*)(y + i);
  int p = (int)(i & (NHW - 1));
  int c = (int)((i >> 12) % NC);
  int z = (int)(i / ((size_t)NC * NHW));
  const float inv = 1.0f / NC;
  float wc = w[c], bc = b[c];
  const float* pp = &g_part[z * NHW + p];
  v.x = v.x * rsqrtf(pp[0] * inv + 1e-5f) * wc + bc;
  v.y = v.y * rsqrtf(pp[1] * inv + 1e-5f) * wc + bc;
  v.z = v.z * rsqrtf(pp[2] * inv + 1e-5f) * wc + bc;
  v.w = v.w * rsqrtf(pp[3] * inv + 1e-5f) * wc + bc;
  *(float4*)(y + i) = v;
}

extern "C" void kernel_launch(void* const* d_in, const int* in_sizes, int n_in,
                              void* d_out, int out_size, void* d_ws, size_t ws_size,
                              hipStream_t stream) {
  const float* x = (const float*)d_in[0];
  const float* wq = (const float*)d_in[1];
  const float* wk = (const float*)d_in[2];
  const float* wv = (const float*)d_in[3];
  const float* wdw = (const float*)d_in[4];
  const float* wpw = (const float*)d_in[5];
  const float* wout = (const float*)d_in[6];
  const float* rw = (const float*)d_in[7];
  const float* rb = (const float*)d_in[8];
  float* y = (float*)d_out;

  convert_weights<<<6480, 256, 0, stream>>>(wq, wk, wv, wout);
  transpose_x<<<dim3(128, 36, 2), dim3(32, 8), 0, stream>>>(x);
  gemm1_kernel<<<dim3(27, 32, 2), 512, 0, stream>>>();
  conv_kernel<<<dim3(16, 432, 2), 256, 0, stream>>>(wdw, wpw);
  attn_kernel<<<dim3(288, 2), 256, 0, stream>>>();
  gemm2_kernel<<<dim3(9, 32, 2), 512, 0, stream>>>(y);
  rms_zero<<<32, 256, 0, stream>>>();
  rms_partial<<<dim3(16, 8, 2), 256, 0, stream>>>(y);
  rms_norm<<<9216, 256, 0, stream>>>(y, rw, rb);
}

// Round 8
// 640.455 us; speedup vs baseline: 2.0090x; 1.3572x over previous
//
#include <hip/hip_runtime.h>

typedef _Float16 f16;
typedef f16 f16x8 __attribute__((ext_vector_type(8)));
typedef float f32x4 __attribute__((ext_vector_type(4)));

#define NB 2
#define NC 1152
#define NHW 4096
#define NCH3 3456
#define NC2 2304

#define LO_SCALE 2048.0f
#define LO_INV (1.0f / 2048.0f)

// persistent scratch (fully overwritten every call)
__device__ __align__(16) f16 g_Wcat_h[(size_t)NCH3 * NC];
__device__ __align__(16) f16 g_Wcat_l[(size_t)NCH3 * NC];
__device__ __align__(16) f16 g_WoutB_h[(size_t)NC * NC2];
__device__ __align__(16) f16 g_XT_h[(size_t)NB * NHW * NC];
__device__ __align__(16) f16 g_XT_l[(size_t)NB * NHW * NC];
__device__ __align__(16) float g_qkv[(size_t)NB * NCH3 * NHW];
__device__ __align__(16) float g_ms[(size_t)NB * NCH3 * NHW];
__device__ __align__(16) f16 g_attnT_h[(size_t)NB * NHW * NC2];
__device__ float g_part[NB * NHW];

__device__ __forceinline__ void gload16(const void* g, void* l) {
  __builtin_amdgcn_global_load_lds(
      (const __attribute__((address_space(1))) unsigned int*)g,
      (__attribute__((address_space(3))) unsigned int*)l, 16, 0, 0);
}

// scaled split: v ~= h + l/2048, with l kept in f16-normal range
__device__ __forceinline__ void split_f16(float v, f16& h, f16& l) {
  h = (f16)v;
  l = (f16)((v - (float)h) * LO_SCALE);
}

// ---------- weight conversion ----------
__global__ __launch_bounds__(256) void convert_weights(
    const float* __restrict__ wq, const float* __restrict__ wk,
    const float* __restrict__ wv, const float* __restrict__ wout) {
  size_t idx = ((size_t)blockIdx.x * 256 + threadIdx.x) * 4;
  const size_t NW = (size_t)NC * NC;
  const size_t NWC = 3 * NW;
  const size_t NWO = (size_t)NC * NC2;
  if (idx < NWC) {
    const float* src = (idx < NW) ? wq + idx
                      : (idx < 2 * NW) ? wk + (idx - NW)
                                       : wv + (idx - 2 * NW);
#pragma unroll
    for (int j = 0; j < 4; ++j)
      split_f16(src[j], g_Wcat_h[idx + j], g_Wcat_l[idx + j]);
  } else {
    size_t k = idx - NWC;
    if (k < NWO) {
      const float* src = wout + k;
#pragma unroll
      for (int j = 0; j < 4; ++j) g_WoutB_h[k + j] = (f16)src[j];
    }
  }
}

// ---------- x (B,C,HW) fp32 -> XT (B,HW,C) scaled-split f16 ----------
__global__ __launch_bounds__(256) void transpose_x(const float* __restrict__ x) {
  __shared__ float tile[32][33];
  int z = blockIdx.z;
  int p0 = blockIdx.x * 32, c0 = blockIdx.y * 32;
  int tx = threadIdx.x, ty = threadIdx.y;
#pragma unroll
  for (int i = 0; i < 32; i += 8)
    tile[ty + i][tx] = x[((size_t)z * NC + c0 + ty + i) * NHW + p0 + tx];
  __syncthreads();
#pragma unroll
  for (int i = 0; i < 32; i += 8) {
    size_t o = ((size_t)z * NHW + p0 + ty + i) * NC + c0 + tx;
    split_f16(tile[tx][ty + i], g_XT_h[o], g_XT_l[o]);
  }
}

// ===== GEMM geometry (both kernels) =====
// 512 threads = 8 waves (2x4). Block tile 128x128, K-step 32.
// LDS tile [128][32] f16, 16B-block swizzle: blk' = blk ^ ((row>>1)&3).
// global_load_lds dest is LINEAR (tid*16); source address pre-swizzled.

// ---------- split-f16 GEMM (fp32 fidelity): C = A @ Bt^T ----------
template <int M, int N, int K>
__device__ __forceinline__ void gemm_body_split(
    const f16* __restrict__ Ah, const f16* __restrict__ Al,
    const f16* __restrict__ Bth, const f16* __restrict__ Btl,
    float* __restrict__ C) {
  __shared__ __align__(16) f16 sAh[128 * 32];
  __shared__ __align__(16) f16 sAl[128 * 32];
  __shared__ __align__(16) f16 sBh[128 * 32];
  __shared__ __align__(16) f16 sBl[128 * 32];
  const int tid = threadIdx.x;
  const int lane = tid & 63;
  const int wid = tid >> 6;
  const int wr = wid >> 2, wc = wid & 3;          // 2x4 waves
  const int bm = blockIdx.x * 128, bn = blockIdx.y * 128;
  const size_t boff = (size_t)blockIdx.z * ((size_t)N * K);
  const f16* Bh = Bth + boff;
  const f16* Bl = Btl + boff;
  float* Cb = C + (size_t)blockIdx.z * ((size_t)M * N);
  // staging: thread -> (row = tid>>2, lds blk = tid&3), source blk swizzled
  const int srow = tid >> 2;
  const int skb = (((tid & 3) ^ ((srow >> 1) & 3)) * 8);
  const f16* gAh = Ah + (size_t)(bm + srow) * K + skb;
  const f16* gAl = Al + (size_t)(bm + srow) * K + skb;
  const f16* gBh = Bh + (size_t)(bn + srow) * K + skb;
  const f16* gBl = Bl + (size_t)(bn + srow) * K + skb;
  char* lAh = (char*)sAh + tid * 16;
  char* lAl = (char*)sAl + tid * 16;
  char* lBh = (char*)sBh + tid * 16;
  char* lBl = (char*)sBl + tid * 16;

  f32x4 acc[4][2] = {};
  f32x4 acc2[4][2] = {};
  const int arow = lane & 15;
  const int swz = (((lane >> 4) ^ ((arow >> 1) & 3)) * 8);  // swizzled 16B blk
#pragma unroll 1
  for (int k0 = 0; k0 < K; k0 += 32) {
    gload16(gAh, lAh);
    gload16(gAl, lAl);
    gload16(gBh, lBh);
    gload16(gBl, lBl);
    gAh += 32; gAl += 32; gBh += 32; gBl += 32;
    __syncthreads();
    f16x8 ah[4], al[4], bh[2], bl[2];
#pragma unroll
    for (int m = 0; m < 4; ++m) {
      int ro = (wr * 64 + m * 16 + arow) * 32 + swz;
      ah[m] = *(const f16x8*)(sAh + ro);
      al[m] = *(const f16x8*)(sAl + ro);
    }
#pragma unroll
    for (int n = 0; n < 2; ++n) {
      int ro = (wc * 32 + n * 16 + arow) * 32 + swz;
      bh[n] = *(const f16x8*)(sBh + ro);
      bl[n] = *(const f16x8*)(sBl + ro);
    }
#pragma unroll
    for (int m = 0; m < 4; ++m)
#pragma unroll
      for (int n = 0; n < 2; ++n) {
        acc[m][n]  = __builtin_amdgcn_mfma_f32_16x16x32_f16(ah[m], bh[n], acc[m][n], 0, 0, 0);
        acc2[m][n] = __builtin_amdgcn_mfma_f32_16x16x32_f16(ah[m], bl[n], acc2[m][n], 0, 0, 0);
        acc2[m][n] = __builtin_amdgcn_mfma_f32_16x16x32_f16(al[m], bh[n], acc2[m][n], 0, 0, 0);
      }
    __syncthreads();
  }
#pragma unroll
  for (int m = 0; m < 4; ++m)
#pragma unroll
    for (int n = 0; n < 2; ++n) {
      int col = bn + wc * 32 + n * 16 + arow;
#pragma unroll
      for (int j = 0; j < 4; ++j) {
        int row = bm + wr * 64 + m * 16 + (lane >> 4) * 4 + j;
        Cb[(size_t)row * N + col] = acc[m][n][j] + acc2[m][n][j] * LO_INV;
      }
    }
}

// ---------- plain f16 GEMM: C = A @ Bt^T ----------
template <int M, int N, int K>
__device__ __forceinline__ void gemm_body_plain(
    const f16* __restrict__ A, const f16* __restrict__ Bt,
    float* __restrict__ C) {
  __shared__ __align__(16) f16 sA[128 * 32];
  __shared__ __align__(16) f16 sB[128 * 32];
  const int tid = threadIdx.x;
  const int lane = tid & 63;
  const int wid = tid >> 6;
  const int wr = wid >> 2, wc = wid & 3;
  const int bm = blockIdx.x * 128, bn = blockIdx.y * 128;
  const f16* Bb = Bt + (size_t)blockIdx.z * ((size_t)N * K);
  float* Cb = C + (size_t)blockIdx.z * ((size_t)M * N);
  const int srow = tid >> 2;
  const int skb = (((tid & 3) ^ ((srow >> 1) & 3)) * 8);
  const f16* gA = A + (size_t)(bm + srow) * K + skb;
  const f16* gB = Bb + (size_t)(bn + srow) * K + skb;
  char* lA = (char*)sA + tid * 16;
  char* lB = (char*)sB + tid * 16;

  f32x4 acc[4][2] = {};
  const int arow = lane & 15;
  const int swz = (((lane >> 4) ^ ((arow >> 1) & 3)) * 8);
#pragma unroll 1
  for (int k0 = 0; k0 < K; k0 += 32) {
    gload16(gA, lA);
    gload16(gB, lB);
    gA += 32; gB += 32;
    __syncthreads();
    f16x8 af[4], bf[2];
#pragma unroll
    for (int m = 0; m < 4; ++m)
      af[m] = *(const f16x8*)(sA + (wr * 64 + m * 16 + arow) * 32 + swz);
#pragma unroll
    for (int n = 0; n < 2; ++n)
      bf[n] = *(const f16x8*)(sB + (wc * 32 + n * 16 + arow) * 32 + swz);
#pragma unroll
    for (int m = 0; m < 4; ++m)
#pragma unroll
      for (int n = 0; n < 2; ++n)
        acc[m][n] = __builtin_amdgcn_mfma_f32_16x16x32_f16(af[m], bf[n], acc[m][n], 0, 0, 0);
    __syncthreads();
  }
#pragma unroll
  for (int m = 0; m < 4; ++m)
#pragma unroll
    for (int n = 0; n < 2; ++n) {
      int col = bn + wc * 32 + n * 16 + arow;
#pragma unroll
      for (int j = 0; j < 4; ++j) {
        int row = bm + wr * 64 + m * 16 + (lane >> 4) * 4 + j;
        Cb[(size_t)row * N + col] = acc[m][n][j];
      }
    }
}

__global__ __launch_bounds__(512) void gemm1_kernel() {
  gemm_body_split<NCH3, NHW, NC>(g_Wcat_h, g_Wcat_l, g_XT_h, g_XT_l, g_qkv);
}
__global__ __launch_bounds__(512) void gemm2_kernel(float* __restrict__ out) {
  gemm_body_plain<NC, NHW, NC2>(g_WoutB_h, g_attnT_h, out);
}

// ---------- fused depthwise 5x5 + grouped 1x1 (fp32, float4-vectorized) ----------
// Each thread computes 4 consecutive pixels for one group of 8 channels.
// Per channel-row: 3 aligned float4 loads cover cols w0-4..w0+7; the four
// 5-col windows are register-selected. Image boundary = zeros.
__global__ __launch_bounds__(256) void conv_kernel(const float* __restrict__ wdw,
                                                   const float* __restrict__ wpw) {
  const int z = blockIdx.z, g = blockIdx.y;
  const int px = blockIdx.x * 1024 + threadIdx.x * 4;  // 4 px/thread
  const int h = px >> 6, w0 = px & 63;                 // w0 in {0,4,...,60}
  const float* base = g_qkv + ((size_t)z * NCH3 + g * 8) * NHW;

  float dw[8][4];
#pragma unroll
  for (int ci = 0; ci < 8; ++ci) {
    const float* wd = wdw + (g * 8 + ci) * 25;
    const float* srcc = base + (size_t)ci * NHW;
    float acc0 = 0.f, acc1 = 0.f, acc2 = 0.f, acc3 = 0.f;
#pragma unroll
    for (int dy = -2; dy <= 2; ++dy) {
      int hh = h + dy;
      if (hh < 0 || hh > 63) continue;
      const float* row = srcc + hh * 64;
      float4 Lv = (w0 >= 4) ? *(const float4*)(row + w0 - 4)
                            : make_float4(0.f, 0.f, 0.f, 0.f);
      float4 Mv = *(const float4*)(row + w0);
      float4 Rv = (w0 <= 56) ? *(const float4*)(row + w0 + 4)
                             : make_float4(0.f, 0.f, 0.f, 0.f);
      float c[12] = {Lv.x, Lv.y, Lv.z, Lv.w, Mv.x, Mv.y, Mv.z, Mv.w,
                     Rv.x, Rv.y, Rv.z, Rv.w};
      const float* wrow = wd + (dy + 2) * 5;
#pragma unroll
      for (int dx = 0; dx < 5; ++dx) {
        float wv = wrow[dx];
        acc0 += c[2 + dx] * wv;
        acc1 += c[3 + dx] * wv;
        acc2 += c[4 + dx] * wv;
        acc3 += c[5 + dx] * wv;
      }
    }
    dw[ci][0] = acc0; dw[ci][1] = acc1; dw[ci][2] = acc2; dw[ci][3] = acc3;
  }
#pragma unroll
  for (int o = 0; o < 8; ++o) {
    const float* wp = wpw + (size_t)(g * 8 + o) * 8;
    float4 out = make_float4(0.f, 0.f, 0.f, 0.f);
#pragma unroll
    for (int i = 0; i < 8; ++i) {
      float wv = wp[i];
      out.x += wv * dw[i][0];
      out.y += wv * dw[i][1];
      out.z += wv * dw[i][2];
      out.w += wv * dw[i][3];
    }
    *(float4*)(g_ms + ((size_t)z * NCH3 + g * 8 + o) * NHW + px) = out;
  }
}

// ---------- linear attention per (group, batch), fp32 ----------
__global__ __launch_bounds__(256) void attn_kernel() {
  int g = blockIdx.x;
  int z = blockIdx.y;
  int tid = threadIdx.x;
  const float* src = (g < 144)
      ? g_qkv + ((size_t)z * NCH3 + g * 24) * NHW
      : g_ms + ((size_t)z * NCH3 + (g - 144) * 24) * NHW;

  float s[9][8];
#pragma unroll
  for (int d = 0; d < 9; ++d)
#pragma unroll
    for (int e = 0; e < 8; ++e) s[d][e] = 0.f;

  for (int p = tid; p < NHW; p += 256) {
    float kv[8], vv[8];
#pragma unroll
    for (int e = 0; e < 8; ++e) kv[e] = fmaxf(src[(size_t)(8 + e) * NHW + p], 0.f);
#pragma unroll
    for (int d = 0; d < 8; ++d) vv[d] = src[(size_t)(16 + d) * NHW + p];
#pragma unroll
    for (int e = 0; e < 8; ++e) {
#pragma unroll
      for (int d = 0; d < 8; ++d) s[d][e] += vv[d] * kv[e];
      s[8][e] += kv[e];
    }
  }
#pragma unroll
  for (int d = 0; d < 9; ++d)
#pragma unroll
    for (int e = 0; e < 8; ++e) {
      float v = s[d][e];
#pragma unroll
      for (int off = 32; off > 0; off >>= 1) v += __shfl_xor(v, off, 64);
      s[d][e] = v;
    }
  __shared__ float sred[4][72];
  __shared__ float sc[72];
  int w = tid >> 6, lane = tid & 63;
  if (lane == 0) {
#pragma unroll
    for (int d = 0; d < 9; ++d)
#pragma unroll
      for (int e = 0; e < 8; ++e) sred[w][d * 8 + e] = s[d][e];
  }
  __syncthreads();
  if (tid < 72) sc[tid] = sred[0][tid] + sred[1][tid] + sred[2][tid] + sred[3][tid];
  __syncthreads();
  float scl[9][8];
#pragma unroll
  for (int d = 0; d < 9; ++d)
#pragma unroll
    for (int e = 0; e < 8; ++e) scl[d][e] = sc[d * 8 + e];

  for (int p = tid; p < NHW; p += 256) {
    float qv[8];
#pragma unroll
    for (int e = 0; e < 8; ++e) qv[e] = fmaxf(src[(size_t)e * NHW + p], 0.f);
    float o[9];
#pragma unroll
    for (int d = 0; d < 9; ++d) {
      float a = 0.f;
#pragma unroll
      for (int e = 0; e < 8; ++e) a += scl[d][e] * qv[e];
      o[d] = a;
    }
    float r = 1.f / (o[8] + 1e-15f);
    f16x8 oh;
#pragma unroll
    for (int d = 0; d < 8; ++d) oh[d] = (f16)(o[d] * r);
    *(f16x8*)(g_attnT_h + ((size_t)z * NHW + p) * NC2 + g * 8) = oh;
  }
}

// ---------- RMSNorm over channel dim, in-place on y ----------
__global__ __launch_bounds__(256) void rms_zero() {
  g_part[blockIdx.x * 256 + threadIdx.x] = 0.f;
}
__global__ __launch_bounds__(256) void rms_partial(const float* __restrict__ y) {
  int z = blockIdx.z, cc = blockIdx.y;
  int p = blockIdx.x * 256 + threadIdx.x;
  float ss = 0.f;
  int cbase = cc * 144;
  for (int c = 0; c < 144; ++c) {
    float v = y[((size_t)z * NC + cbase + c) * NHW + p];
    ss += v * v;
  }
  atomicAdd(&g_part[z * NHW + p], ss);
}
__global__ __launch_bounds__(256) void rms_norm(float* __restrict__ y,
                                                const float* __restrict__ w,
                                                const float* __restrict__ b) {
  size_t i = ((size_t)blockIdx.x * 256 + threadIdx.x) * 4;
  float4 v = *(const float4*)(y + i);
  int p = (int)(i & (NHW - 1));
  int c = (int)((i >> 12) % NC);
  int z = (int)(i / ((size_t)NC * NHW));
  const float inv = 1.0f / NC;
  float wc = w[c], bc = b[c];
  const float* pp = &g_part[z * NHW + p];
  v.x = v.x * rsqrtf(pp[0] * inv + 1e-5f) * wc + bc;
  v.y = v.y * rsqrtf(pp[1] * inv + 1e-5f) * wc + bc;
  v.z = v.z * rsqrtf(pp[2] * inv + 1e-5f) * wc + bc;
  v.w = v.w * rsqrtf(pp[3] * inv + 1e-5f) * wc + bc;
  *(float4*)(y + i) = v;
}

extern "C" void kernel_launch(void* const* d_in, const int* in_sizes, int n_in,
                              void* d_out, int out_size, void* d_ws, size_t ws_size,
                              hipStream_t stream) {
  const float* x = (const float*)d_in[0];
  const float* wq = (const float*)d_in[1];
  const float* wk = (const float*)d_in[2];
  const float* wv = (const float*)d_in[3];
  const float* wdw = (const float*)d_in[4];
  const float* wpw = (const float*)d_in[5];
  const float* wout = (const float*)d_in[6];
  const float* rw = (const float*)d_in[7];
  const float* rb = (const float*)d_in[8];
  float* y = (float*)d_out;

  convert_weights<<<6480, 256, 0, stream>>>(wq, wk, wv, wout);
  transpose_x<<<dim3(128, 36, 2), dim3(32, 8), 0, stream>>>(x);
  gemm1_kernel<<<dim3(27, 32, 2), 512, 0, stream>>>();
  conv_kernel<<<dim3(4, 432, 2), 256, 0, stream>>>(wdw, wpw);
  attn_kernel<<<dim3(288, 2), 256, 0, stream>>>();
  gemm2_kernel<<<dim3(9, 32, 2), 512, 0, stream>>>(y);
  rms_zero<<<32, 256, 0, stream>>>();
  rms_partial<<<dim3(16, 8, 2), 256, 0, stream>>>(y);
  rms_norm<<<9216, 256, 0, stream>>>(y, rw, rb);
}